// Round 6
// baseline (429.544 us; speedup 1.0000x reference)
//
#include <hip/hip_runtime.h>
#include <math.h>

// Problem constants (fixed by the reference)
#define BB 256
#define TT 512
#define DD 128
#define HH 128
#define GG 512   // 4*H
#define OO 64

typedef _Float16 half8 __attribute__((ext_vector_type(8)));
typedef float    f32x4 __attribute__((ext_vector_type(4)));

// ---------------------------------------------------------------------------
// Fast activations (fp32; threshold 5.6e-3, plenty of headroom)
// ---------------------------------------------------------------------------
__device__ __forceinline__ float sigmoid_fast(float x) {
    return 1.0f / (1.0f + __expf(-x));
}
__device__ __forceinline__ float tanh_fast(float x) {
    float ax = fabsf(x);
    float e = __expf(2.0f * ax);
    float t = 1.0f - 2.0f / (e + 1.0f);
    return copysignf(t, x);
}

// ---------------------------------------------------------------------------
// Kernel 1: xg[t][g] = dot(x[255,t,:], W_ih[g,:]) + b_ih[g] + b_hh[g]
// Only batch 255 matters: y.reshape(T,B,O)[-1] -> flat rows (b=255, t>=256),
// and b=255's scan needs all t. grid = T, block = 512.
// ---------------------------------------------------------------------------
__global__ __launch_bounds__(512) void xg_kernel(
    const float* __restrict__ x,
    const float* __restrict__ W_ih,
    const float* __restrict__ b_ih,
    const float* __restrict__ b_hh,
    float* __restrict__ xg)
{
    const int t = blockIdx.x;
    const int g = threadIdx.x;

    __shared__ __align__(16) float xs[DD];
    if (g < DD) xs[g] = x[(255 * TT + t) * DD + g];
    __syncthreads();

    const float4* __restrict__ wrow = (const float4*)(W_ih + g * DD);
    const float4* __restrict__ xv   = (const float4*)xs;

    float a0 = 0.f, a1 = 0.f, a2 = 0.f, a3 = 0.f;
#pragma unroll
    for (int i = 0; i < DD / 4; i += 4) {
        float4 w0 = wrow[i + 0], w1 = wrow[i + 1], w2 = wrow[i + 2], w3 = wrow[i + 3];
        float4 h0 = xv[i + 0],  h1 = xv[i + 1],  h2 = xv[i + 2],  h3 = xv[i + 3];
        a0 += w0.x * h0.x + w0.y * h0.y + w0.z * h0.z + w0.w * h0.w;
        a1 += w1.x * h1.x + w1.y * h1.y + w1.z * h1.z + w1.w * h1.w;
        a2 += w2.x * h2.x + w2.y * h2.y + w2.z * h2.z + w2.w * h2.w;
        a3 += w3.x * h3.x + w3.y * h3.y + w3.z * h3.z + w3.w * h3.w;
    }
    xg[t * GG + g] = (a0 + a1) + (a2 + a3) + b_ih[g] + b_hh[g];
}

// ---------------------------------------------------------------------------
// Kernel 2: MFMA LSTM scan (batch 255). 1 block, 512 threads = 8 waves.
//
// Wave w owns hidden slice [16w, 16w+16) for ALL 4 gate types:
//   B-frag (gt,kt): gate row gt*128 + 16w + col, elems kt*32 + quad*8.
//   16 frags = 64 VGPRs/wave. A-frag: h replicated over all 16 rows
//   (every C row = the matvec). C/D: col = lane&15 -> lane computes
//   i,f,g,o for hidden j = 16w+col directly -- no cndmask select at all.
//
// Fixes for the r3-r5 ~1400 cyc/step invariant:
//  - "+v" in-loop pin (NOT "+a"): r5's AGPR pin induced ~128
//    v_accvgpr_read copies/step. "+v" keeps frags in VGPRs (MFMA-native),
//    in-loop redefinition still makes load sinking illegal.
//  - distance-2 xg pipeline with alternating reg sets (no rotation movs):
//    xg is HBM-latency (~900 cyc) for this CU (written by other XCDs'
//    L2s); r3-r5 rotated via a copy that forced vmcnt(0) in the SAME
//    iteration. Even/odd sets give ~1.7 iterations of slack.
//  - 8 waves = 2/SIMD: overlaps exposed LDS/MFMA/transcendental latency.
// ---------------------------------------------------------------------------
__global__
__attribute__((amdgpu_flat_work_group_size(512, 512), amdgpu_waves_per_eu(2, 2)))
void scan_kernel(
    const float* __restrict__ Wf,
    const float* __restrict__ xgp,
    float* __restrict__ hs)
{
    const int tid  = threadIdx.x;
    const int lane = tid & 63;
    const int w    = tid >> 6;        // wave id 0..7
    const int col  = lane & 15;
    const int quad = lane >> 4;
    const int wbase = w * 16;
    const int jsel  = wbase + col;    // hidden index this lane computes
    const int aoff  = quad * 8;

    __shared__ __align__(16) _Float16 h_lds[2][HH];

    // ---- one-time: 16 B-fragments f32 -> f16 into named registers ----
#define BLOAD(gt, kt) \
    half8 B##gt##_##kt; { \
        const float* p = Wf + ((gt) * 128 + jsel) * HH + (kt) * 32 + aoff; \
        float4 u = *(const float4*)p; \
        float4 v = *(const float4*)(p + 4); \
        B##gt##_##kt[0] = (_Float16)u.x; B##gt##_##kt[1] = (_Float16)u.y; \
        B##gt##_##kt[2] = (_Float16)u.z; B##gt##_##kt[3] = (_Float16)u.w; \
        B##gt##_##kt[4] = (_Float16)v.x; B##gt##_##kt[5] = (_Float16)v.y; \
        B##gt##_##kt[6] = (_Float16)v.z; B##gt##_##kt[7] = (_Float16)v.w; }
    BLOAD(0,0) BLOAD(0,1) BLOAD(0,2) BLOAD(0,3)
    BLOAD(1,0) BLOAD(1,1) BLOAD(1,2) BLOAD(1,3)
    BLOAD(2,0) BLOAD(2,1) BLOAD(2,2) BLOAD(2,3)
    BLOAD(3,0) BLOAD(3,1) BLOAD(3,2) BLOAD(3,3)

    if (tid < HH) h_lds[0][tid] = (_Float16)0.f;
    float c = 0.f;

    // xg pipeline: even set (e*) preloaded with row 0, odd set (o*) row 1.
    float e0 = xgp[0 * HH + jsel], e1 = xgp[1 * HH + jsel],
          e2 = xgp[2 * HH + jsel], e3 = xgp[3 * HH + jsel];
    float o0 = xgp[GG + 0 * HH + jsel], o1 = xgp[GG + 1 * HH + jsel],
          o2 = xgp[GG + 2 * HH + jsel], o3 = xgp[GG + 3 * HH + jsel];

    __syncthreads();

    int p = 0;

    // One timestep. Consumes (X0..X3) = xg row t, then reloads them with
    // row t+2 (consume-before-reload: no WAR hazard, ~2 iterations of slack).
#define STEP(t, X0, X1, X2, X3) { \
        asm volatile("" : "+v"(B0_0), "+v"(B0_1), "+v"(B0_2), "+v"(B0_3), \
                          "+v"(B1_0), "+v"(B1_1), "+v"(B1_2), "+v"(B1_3), \
                          "+v"(B2_0), "+v"(B2_1), "+v"(B2_2), "+v"(B2_3), \
                          "+v"(B3_0), "+v"(B3_1), "+v"(B3_2), "+v"(B3_3)); \
        const _Float16* hl = h_lds[p]; \
        half8 A0 = *(const half8*)(hl + 0 * 32 + aoff); \
        half8 A1 = *(const half8*)(hl + 1 * 32 + aoff); \
        half8 A2 = *(const half8*)(hl + 2 * 32 + aoff); \
        half8 A3 = *(const half8*)(hl + 3 * 32 + aoff); \
        f32x4 C0 = {0.f,0.f,0.f,0.f}, C1 = {0.f,0.f,0.f,0.f}; \
        f32x4 C2 = {0.f,0.f,0.f,0.f}, C3 = {0.f,0.f,0.f,0.f}; \
        C0 = __builtin_amdgcn_mfma_f32_16x16x32_f16(A0, B0_0, C0, 0, 0, 0); \
        C1 = __builtin_amdgcn_mfma_f32_16x16x32_f16(A0, B1_0, C1, 0, 0, 0); \
        C2 = __builtin_amdgcn_mfma_f32_16x16x32_f16(A0, B2_0, C2, 0, 0, 0); \
        C3 = __builtin_amdgcn_mfma_f32_16x16x32_f16(A0, B3_0, C3, 0, 0, 0); \
        C0 = __builtin_amdgcn_mfma_f32_16x16x32_f16(A1, B0_1, C0, 0, 0, 0); \
        C1 = __builtin_amdgcn_mfma_f32_16x16x32_f16(A1, B1_1, C1, 0, 0, 0); \
        C2 = __builtin_amdgcn_mfma_f32_16x16x32_f16(A1, B2_1, C2, 0, 0, 0); \
        C3 = __builtin_amdgcn_mfma_f32_16x16x32_f16(A1, B3_1, C3, 0, 0, 0); \
        C0 = __builtin_amdgcn_mfma_f32_16x16x32_f16(A2, B0_2, C0, 0, 0, 0); \
        C1 = __builtin_amdgcn_mfma_f32_16x16x32_f16(A2, B1_2, C1, 0, 0, 0); \
        C2 = __builtin_amdgcn_mfma_f32_16x16x32_f16(A2, B2_2, C2, 0, 0, 0); \
        C3 = __builtin_amdgcn_mfma_f32_16x16x32_f16(A2, B3_2, C3, 0, 0, 0); \
        C0 = __builtin_amdgcn_mfma_f32_16x16x32_f16(A3, B0_3, C0, 0, 0, 0); \
        C1 = __builtin_amdgcn_mfma_f32_16x16x32_f16(A3, B1_3, C1, 0, 0, 0); \
        C2 = __builtin_amdgcn_mfma_f32_16x16x32_f16(A3, B2_3, C2, 0, 0, 0); \
        C3 = __builtin_amdgcn_mfma_f32_16x16x32_f16(A3, B3_3, C3, 0, 0, 0); \
        float iv = sigmoid_fast(C0[0] + X0); \
        float fv = sigmoid_fast(C1[0] + X1); \
        float gv = tanh_fast(C2[0] + X2); \
        float ov = sigmoid_fast(C3[0] + X3); \
        c = fv * c + iv * gv; \
        float hval = ov * tanh_fast(c); \
        if (quad == 0) { \
            h_lds[1 - p][jsel] = (_Float16)hval; \
            if ((t) >= TT - BB) hs[((t) - (TT - BB)) * HH + jsel] = hval; \
        } \
        const int tn = ((t) + 2 < TT) ? ((t) + 2) : (TT - 1); \
        X0 = xgp[tn * GG + 0 * HH + jsel]; \
        X1 = xgp[tn * GG + 1 * HH + jsel]; \
        X2 = xgp[tn * GG + 2 * HH + jsel]; \
        X3 = xgp[tn * GG + 3 * HH + jsel]; \
        p ^= 1; \
        __syncthreads(); \
    }

    for (int t = 0; t < TT; t += 2) {
        STEP(t,     e0, e1, e2, e3)
        STEP(t + 1, o0, o1, o2, o3)
    }
}

// ---------------------------------------------------------------------------
// Kernel 3: out[r,:] = W2 @ (W1 @ hs[r] + b1) + b2  (no activation in ref)
// ---------------------------------------------------------------------------
__global__ __launch_bounds__(128) void mlp_kernel(
    const float* __restrict__ hs,
    const float* __restrict__ W1,
    const float* __restrict__ b1,
    const float* __restrict__ W2,
    const float* __restrict__ b2,
    float* __restrict__ out)
{
    const int r = blockIdx.x;
    const int j = threadIdx.x;

    __shared__ __align__(16) float hsh[HH];
    __shared__ __align__(16) float z[HH];

    hsh[j] = hs[r * HH + j];
    __syncthreads();

    {
        const float4* __restrict__ wrow = (const float4*)(W1 + j * HH);
        const float4* __restrict__ hv   = (const float4*)hsh;
        float acc = b1[j];
#pragma unroll
        for (int i = 0; i < 32; i++) {
            float4 ww = wrow[i], h = hv[i];
            acc += ww.x * h.x + ww.y * h.y + ww.z * h.z + ww.w * h.w;
        }
        z[j] = acc;
    }
    __syncthreads();

    if (j < OO) {
        const float4* __restrict__ wrow = (const float4*)(W2 + j * HH);
        const float4* __restrict__ zv   = (const float4*)z;
        float acc = b2[j];
#pragma unroll
        for (int i = 0; i < 32; i++) {
            float4 ww = wrow[i], zz = zv[i];
            acc += ww.x * zz.x + ww.y * zz.y + ww.z * zz.z + ww.w * zz.w;
        }
        out[r * OO + j] = acc;
    }
}

// ---------------------------------------------------------------------------
// Launch. Inputs: 0:x 1:W_ih 2:W_hh 3:b_ih 4:b_hh 5:W1 6:b1 7:W2 8:b2
// ws: xg (1 MB) | hs (128 KB)
// ---------------------------------------------------------------------------
extern "C" void kernel_launch(void* const* d_in, const int* in_sizes, int n_in,
                              void* d_out, int out_size, void* d_ws, size_t ws_size,
                              hipStream_t stream) {
    const float* x    = (const float*)d_in[0];
    const float* W_ih = (const float*)d_in[1];
    const float* W_hh = (const float*)d_in[2];
    const float* b_ih = (const float*)d_in[3];
    const float* b_hh = (const float*)d_in[4];
    const float* W1   = (const float*)d_in[5];
    const float* b1   = (const float*)d_in[6];
    const float* W2   = (const float*)d_in[7];
    const float* b2   = (const float*)d_in[8];
    float* out = (float*)d_out;

    float* xg = (float*)d_ws;            // T*4H = 262144 f32
    float* hs = xg + TT * GG;            // 256*H = 32768 f32

    xg_kernel<<<TT, 512, 0, stream>>>(x, W_ih, b_ih, b_hh, xg);
    scan_kernel<<<1, 512, 0, stream>>>(W_hh, xg, hs);
    mlp_kernel<<<BB, 128, 0, stream>>>(hs, W1, b1, W2, b2, out);
}

// Round 7
// 426.972 us; speedup vs baseline: 1.0060x; 1.0060x over previous
//
#include <hip/hip_runtime.h>
#include <math.h>

// Problem constants (fixed by the reference)
#define BB 256
#define TT 512
#define DD 128
#define HH 128
#define GG 512   // 4*H
#define OO 64

typedef _Float16 half8 __attribute__((ext_vector_type(8)));
typedef float    f32x4 __attribute__((ext_vector_type(4)));

// ---------------------------------------------------------------------------
// Fast activations (fp32; threshold 5.6e-3, plenty of headroom)
// ---------------------------------------------------------------------------
__device__ __forceinline__ float sigmoid_fast(float x) {
    return 1.0f / (1.0f + __expf(-x));
}
__device__ __forceinline__ float tanh_fast(float x) {
    float ax = fabsf(x);
    float e = __expf(2.0f * ax);
    float t = 1.0f - 2.0f / (e + 1.0f);
    return copysignf(t, x);
}

// Raw workgroup barrier that waits ONLY on LDS ops (lgkmcnt), NOT vmcnt.
// __syncthreads() emits s_waitcnt vmcnt(0) lgkmcnt(0) before s_barrier,
// which synchronously drains our xg prefetch to HBM every step (the r3-r6
// ~1435 cyc/step invariant). Opaque inline asm is not treated as a barrier
// by the waitcnt pass, so global loads stay in flight across it.
__device__ __forceinline__ void barrier_lds_only() {
    asm volatile("s_waitcnt lgkmcnt(0)\n\ts_barrier" ::: "memory");
}

// ---------------------------------------------------------------------------
// Kernel 1: xg[t][g] = dot(x[255,t,:], W_ih[g,:]) + b_ih[g] + b_hh[g]
// Only batch 255 matters: y.reshape(T,B,O)[-1] -> flat rows (b=255, t>=256),
// and b=255's scan needs all t. grid = T, block = 512.
// ---------------------------------------------------------------------------
__global__ __launch_bounds__(512) void xg_kernel(
    const float* __restrict__ x,
    const float* __restrict__ W_ih,
    const float* __restrict__ b_ih,
    const float* __restrict__ b_hh,
    float* __restrict__ xg)
{
    const int t = blockIdx.x;
    const int g = threadIdx.x;

    __shared__ __align__(16) float xs[DD];
    if (g < DD) xs[g] = x[(255 * TT + t) * DD + g];
    __syncthreads();

    const float4* __restrict__ wrow = (const float4*)(W_ih + g * DD);
    const float4* __restrict__ xv   = (const float4*)xs;

    float a0 = 0.f, a1 = 0.f, a2 = 0.f, a3 = 0.f;
#pragma unroll
    for (int i = 0; i < DD / 4; i += 4) {
        float4 w0 = wrow[i + 0], w1 = wrow[i + 1], w2 = wrow[i + 2], w3 = wrow[i + 3];
        float4 h0 = xv[i + 0],  h1 = xv[i + 1],  h2 = xv[i + 2],  h3 = xv[i + 3];
        a0 += w0.x * h0.x + w0.y * h0.y + w0.z * h0.z + w0.w * h0.w;
        a1 += w1.x * h1.x + w1.y * h1.y + w1.z * h1.z + w1.w * h1.w;
        a2 += w2.x * h2.x + w2.y * h2.y + w2.z * h2.z + w2.w * h2.w;
        a3 += w3.x * h3.x + w3.y * h3.y + w3.z * h3.z + w3.w * h3.w;
    }
    xg[t * GG + g] = (a0 + a1) + (a2 + a3) + b_ih[g] + b_hh[g];
}

// ---------------------------------------------------------------------------
// Kernel 2: MFMA LSTM scan (batch 255). 1 block, 512 threads = 8 waves.
//
// Wave w owns hidden slice [16w, 16w+16) for ALL 4 gate types:
//   B-frag (gt,kt): gate row gt*128 + 16w + col, elems kt*32 + quad*8.
//   16 frags = 64 VGPRs/wave. A-frag: h replicated over all 16 rows
//   (every C row = the matvec). C/D: col = lane&15 -> lane computes
//   i,f,g,o for hidden j = 16w+col directly -- no cross-lane epilogue.
//
//  - "+v" in-loop pin: keeps B-frags register-resident (remat illegal),
//    MFMA-native VGPRs (r5's "+a" pin induced accvgpr copies).
//  - distance-2 xg prefetch (even/odd reg sets, consume-before-reload).
//  - barrier_lds_only(): the critical fix -- see comment above.
// ---------------------------------------------------------------------------
__global__
__attribute__((amdgpu_flat_work_group_size(512, 512), amdgpu_waves_per_eu(2, 2)))
void scan_kernel(
    const float* __restrict__ Wf,
    const float* __restrict__ xgp,
    float* __restrict__ hs)
{
    const int tid  = threadIdx.x;
    const int lane = tid & 63;
    const int w    = tid >> 6;        // wave id 0..7
    const int col  = lane & 15;
    const int quad = lane >> 4;
    const int wbase = w * 16;
    const int jsel  = wbase + col;    // hidden index this lane computes
    const int aoff  = quad * 8;

    __shared__ __align__(16) _Float16 h_lds[2][HH];

    // ---- one-time: 16 B-fragments f32 -> f16 into named registers ----
#define BLOAD(gt, kt) \
    half8 B##gt##_##kt; { \
        const float* p = Wf + ((gt) * 128 + jsel) * HH + (kt) * 32 + aoff; \
        float4 u = *(const float4*)p; \
        float4 v = *(const float4*)(p + 4); \
        B##gt##_##kt[0] = (_Float16)u.x; B##gt##_##kt[1] = (_Float16)u.y; \
        B##gt##_##kt[2] = (_Float16)u.z; B##gt##_##kt[3] = (_Float16)u.w; \
        B##gt##_##kt[4] = (_Float16)v.x; B##gt##_##kt[5] = (_Float16)v.y; \
        B##gt##_##kt[6] = (_Float16)v.z; B##gt##_##kt[7] = (_Float16)v.w; }
    BLOAD(0,0) BLOAD(0,1) BLOAD(0,2) BLOAD(0,3)
    BLOAD(1,0) BLOAD(1,1) BLOAD(1,2) BLOAD(1,3)
    BLOAD(2,0) BLOAD(2,1) BLOAD(2,2) BLOAD(2,3)
    BLOAD(3,0) BLOAD(3,1) BLOAD(3,2) BLOAD(3,3)

    if (tid < HH) h_lds[0][tid] = (_Float16)0.f;
    float c = 0.f;

    // xg pipeline: even set (e*) preloaded with row 0, odd set (o*) row 1.
    float e0 = xgp[0 * HH + jsel], e1 = xgp[1 * HH + jsel],
          e2 = xgp[2 * HH + jsel], e3 = xgp[3 * HH + jsel];
    float o0 = xgp[GG + 0 * HH + jsel], o1 = xgp[GG + 1 * HH + jsel],
          o2 = xgp[GG + 2 * HH + jsel], o3 = xgp[GG + 3 * HH + jsel];

    __syncthreads();   // full drain once (weights + init), outside the loop

    int p = 0;

    // One timestep. Consumes (X0..X3) = xg row t, then reloads them with
    // row t+2 (consume-before-reload: no WAR hazard, ~2 steps of slack ->
    // in-flight across the raw barriers, covering HBM latency).
#define STEP(t, X0, X1, X2, X3) { \
        asm volatile("" : "+v"(B0_0), "+v"(B0_1), "+v"(B0_2), "+v"(B0_3), \
                          "+v"(B1_0), "+v"(B1_1), "+v"(B1_2), "+v"(B1_3), \
                          "+v"(B2_0), "+v"(B2_1), "+v"(B2_2), "+v"(B2_3), \
                          "+v"(B3_0), "+v"(B3_1), "+v"(B3_2), "+v"(B3_3)); \
        const _Float16* hl = h_lds[p]; \
        half8 A0 = *(const half8*)(hl + 0 * 32 + aoff); \
        half8 A1 = *(const half8*)(hl + 1 * 32 + aoff); \
        half8 A2 = *(const half8*)(hl + 2 * 32 + aoff); \
        half8 A3 = *(const half8*)(hl + 3 * 32 + aoff); \
        f32x4 C0 = {0.f,0.f,0.f,0.f}, C1 = {0.f,0.f,0.f,0.f}; \
        f32x4 C2 = {0.f,0.f,0.f,0.f}, C3 = {0.f,0.f,0.f,0.f}; \
        C0 = __builtin_amdgcn_mfma_f32_16x16x32_f16(A0, B0_0, C0, 0, 0, 0); \
        C1 = __builtin_amdgcn_mfma_f32_16x16x32_f16(A0, B1_0, C1, 0, 0, 0); \
        C2 = __builtin_amdgcn_mfma_f32_16x16x32_f16(A0, B2_0, C2, 0, 0, 0); \
        C3 = __builtin_amdgcn_mfma_f32_16x16x32_f16(A0, B3_0, C3, 0, 0, 0); \
        C0 = __builtin_amdgcn_mfma_f32_16x16x32_f16(A1, B0_1, C0, 0, 0, 0); \
        C1 = __builtin_amdgcn_mfma_f32_16x16x32_f16(A1, B1_1, C1, 0, 0, 0); \
        C2 = __builtin_amdgcn_mfma_f32_16x16x32_f16(A1, B2_1, C2, 0, 0, 0); \
        C3 = __builtin_amdgcn_mfma_f32_16x16x32_f16(A1, B3_1, C3, 0, 0, 0); \
        C0 = __builtin_amdgcn_mfma_f32_16x16x32_f16(A2, B0_2, C0, 0, 0, 0); \
        C1 = __builtin_amdgcn_mfma_f32_16x16x32_f16(A2, B1_2, C1, 0, 0, 0); \
        C2 = __builtin_amdgcn_mfma_f32_16x16x32_f16(A2, B2_2, C2, 0, 0, 0); \
        C3 = __builtin_amdgcn_mfma_f32_16x16x32_f16(A2, B3_2, C3, 0, 0, 0); \
        C0 = __builtin_amdgcn_mfma_f32_16x16x32_f16(A3, B0_3, C0, 0, 0, 0); \
        C1 = __builtin_amdgcn_mfma_f32_16x16x32_f16(A3, B1_3, C1, 0, 0, 0); \
        C2 = __builtin_amdgcn_mfma_f32_16x16x32_f16(A3, B2_3, C2, 0, 0, 0); \
        C3 = __builtin_amdgcn_mfma_f32_16x16x32_f16(A3, B3_3, C3, 0, 0, 0); \
        float iv = sigmoid_fast(C0[0] + X0); \
        float fv = sigmoid_fast(C1[0] + X1); \
        float gv = tanh_fast(C2[0] + X2); \
        float ov = sigmoid_fast(C3[0] + X3); \
        c = fv * c + iv * gv; \
        float hval = ov * tanh_fast(c); \
        if (quad == 0) { \
            h_lds[1 - p][jsel] = (_Float16)hval; \
            if ((t) >= TT - BB) hs[((t) - (TT - BB)) * HH + jsel] = hval; \
        } \
        const int tn = ((t) + 2 < TT) ? ((t) + 2) : (TT - 1); \
        X0 = xgp[tn * GG + 0 * HH + jsel]; \
        X1 = xgp[tn * GG + 1 * HH + jsel]; \
        X2 = xgp[tn * GG + 2 * HH + jsel]; \
        X3 = xgp[tn * GG + 3 * HH + jsel]; \
        p ^= 1; \
        barrier_lds_only(); \
    }

    for (int t = 0; t < TT; t += 2) {
        STEP(t,     e0, e1, e2, e3)
        STEP(t + 1, o0, o1, o2, o3)
    }
}

// ---------------------------------------------------------------------------
// Kernel 3: out[r,:] = W2 @ (W1 @ hs[r] + b1) + b2  (no activation in ref)
// ---------------------------------------------------------------------------
__global__ __launch_bounds__(128) void mlp_kernel(
    const float* __restrict__ hs,
    const float* __restrict__ W1,
    const float* __restrict__ b1,
    const float* __restrict__ W2,
    const float* __restrict__ b2,
    float* __restrict__ out)
{
    const int r = blockIdx.x;
    const int j = threadIdx.x;

    __shared__ __align__(16) float hsh[HH];
    __shared__ __align__(16) float z[HH];

    hsh[j] = hs[r * HH + j];
    __syncthreads();

    {
        const float4* __restrict__ wrow = (const float4*)(W1 + j * HH);
        const float4* __restrict__ hv   = (const float4*)hsh;
        float acc = b1[j];
#pragma unroll
        for (int i = 0; i < 32; i++) {
            float4 ww = wrow[i], h = hv[i];
            acc += ww.x * h.x + ww.y * h.y + ww.z * h.z + ww.w * h.w;
        }
        z[j] = acc;
    }
    __syncthreads();

    if (j < OO) {
        const float4* __restrict__ wrow = (const float4*)(W2 + j * HH);
        const float4* __restrict__ zv   = (const float4*)z;
        float acc = b2[j];
#pragma unroll
        for (int i = 0; i < 32; i++) {
            float4 ww = wrow[i], zz = zv[i];
            acc += ww.x * zz.x + ww.y * zz.y + ww.z * zz.z + ww.w * zz.w;
        }
        out[r * OO + j] = acc;
    }
}

// ---------------------------------------------------------------------------
// Launch. Inputs: 0:x 1:W_ih 2:W_hh 3:b_ih 4:b_hh 5:W1 6:b1 7:W2 8:b2
// ws: xg (1 MB) | hs (128 KB)
// ---------------------------------------------------------------------------
extern "C" void kernel_launch(void* const* d_in, const int* in_sizes, int n_in,
                              void* d_out, int out_size, void* d_ws, size_t ws_size,
                              hipStream_t stream) {
    const float* x    = (const float*)d_in[0];
    const float* W_ih = (const float*)d_in[1];
    const float* W_hh = (const float*)d_in[2];
    const float* b_ih = (const float*)d_in[3];
    const float* b_hh = (const float*)d_in[4];
    const float* W1   = (const float*)d_in[5];
    const float* b1   = (const float*)d_in[6];
    const float* W2   = (const float*)d_in[7];
    const float* b2   = (const float*)d_in[8];
    float* out = (float*)d_out;

    float* xg = (float*)d_ws;            // T*4H = 262144 f32
    float* hs = xg + TT * GG;            // 256*H = 32768 f32

    xg_kernel<<<TT, 512, 0, stream>>>(x, W_ih, b_ih, b_hh, xg);
    scan_kernel<<<1, 512, 0, stream>>>(W_hh, xg, hs);
    mlp_kernel<<<BB, 128, 0, stream>>>(hs, W1, b1, W2, b2, out);
}

// Round 8
// 388.841 us; speedup vs baseline: 1.1047x; 1.0981x over previous
//
#include <hip/hip_runtime.h>
#include <math.h>

// Problem constants (fixed by the reference)
#define BB 256
#define TT 512
#define DD 128
#define HH 128
#define GG 512   // 4*H
#define OO 64
#define NCH (TT / 4)   // 128 chunks of 4 timesteps

typedef _Float16 half8 __attribute__((ext_vector_type(8)));
typedef float    f32x4 __attribute__((ext_vector_type(4)));

// ---------------------------------------------------------------------------
// Fast activations (fp32; threshold 5.6e-3, plenty of headroom)
// ---------------------------------------------------------------------------
__device__ __forceinline__ float sigmoid_fast(float x) {
    return 1.0f / (1.0f + __expf(-x));
}
__device__ __forceinline__ float tanh_fast(float x) {
    float ax = fabsf(x);
    float e = __expf(2.0f * ax);
    float t = 1.0f - 2.0f / (e + 1.0f);
    return copysignf(t, x);
}

// ---------------------------------------------------------------------------
// Kernel 0: pack W_hh into per-lane MFMA B-fragments (f16, 16B contiguous).
// Fragment math copied verbatim from the r3 scan (numerically verified):
//   wave w, n-tile nt (0..7), k-tile kt (0..3), lane l:
//   row = (nt>>1)*128 + (nt&1)*16 + w*32 + (l&15); off = kt*32 + (l>>4)*8
//   dst = Wp[((w*32 + nt*4 + kt)*64 + l)*8 .. +8]
// 8192 items, one per thread. One-time, ~3 us.
// ---------------------------------------------------------------------------
__global__ __launch_bounds__(256) void wpack_kernel(
    const float* __restrict__ Wf, _Float16* __restrict__ Wp)
{
    const int g = blockIdx.x * 256 + threadIdx.x;   // grid = 32 -> 8192
    const int fid = g >> 6, l = g & 63;
    const int w = fid >> 5, rem = fid & 31, nt = rem >> 2, kt = rem & 3;
    const int quad = l >> 4, col = l & 15;
    const int row = (nt >> 1) * 128 + (nt & 1) * 16 + w * 32 + col;
    const int off = kt * 32 + quad * 8;
    const float* s = Wf + row * HH + off;
    _Float16* d = Wp + (size_t)g * 8;
#pragma unroll
    for (int i = 0; i < 8; i++) d[i] = (_Float16)s[i];
}

// ---------------------------------------------------------------------------
// Kernel 1: xg[t][j][gt] = dot(x[255,t,:], W_ih[gt*128+j,:]) + b_ih + b_hh
// PACKED per-hidden-index: the scan's lane reads its 4 gate values (i,f,g,o)
// as one 16-B LDS vector. Only batch 255 matters: y.reshape(T,B,O)[-1] ->
// flat rows (b=255, t>=256); b=255's scan needs all t. grid = T, block = 512.
// ---------------------------------------------------------------------------
__global__ __launch_bounds__(512) void xg_kernel(
    const float* __restrict__ x,
    const float* __restrict__ W_ih,
    const float* __restrict__ b_ih,
    const float* __restrict__ b_hh,
    float* __restrict__ xg)
{
    const int t = blockIdx.x;
    const int g = threadIdx.x;

    __shared__ __align__(16) float xs[DD];
    if (g < DD) xs[g] = x[(255 * TT + t) * DD + g];
    __syncthreads();

    const float4* __restrict__ wrow = (const float4*)(W_ih + g * DD);
    const float4* __restrict__ xv   = (const float4*)xs;

    float a0 = 0.f, a1 = 0.f, a2 = 0.f, a3 = 0.f;
#pragma unroll
    for (int i = 0; i < DD / 4; i += 4) {
        float4 w0 = wrow[i + 0], w1 = wrow[i + 1], w2 = wrow[i + 2], w3 = wrow[i + 3];
        float4 h0 = xv[i + 0],  h1 = xv[i + 1],  h2 = xv[i + 2],  h3 = xv[i + 3];
        a0 += w0.x * h0.x + w0.y * h0.y + w0.z * h0.z + w0.w * h0.w;
        a1 += w1.x * h1.x + w1.y * h1.y + w1.z * h1.z + w1.w * h1.w;
        a2 += w2.x * h2.x + w2.y * h2.y + w2.z * h2.z + w2.w * h2.w;
        a3 += w3.x * h3.x + w3.y * h3.y + w3.z * h3.z + w3.w * h3.w;
    }
    const float val = (a0 + a1) + (a2 + a3) + b_ih[g] + b_hh[g];
    // packed: [t][j = g&127][gate = g>>7]
    xg[t * GG + (g & 127) * 4 + (g >> 7)] = val;
}

// ---------------------------------------------------------------------------
// Kernel 2: MFMA LSTM scan (batch 255). 1 block, 256 threads = 4 waves.
// r3's verified tile mapping: wave w owns 8 n-tiles (4 gates x 2 halves) of
// hidden slice [32w, 32w+32); lane updates jsel = 32w + 16*sel + col.
//
// Design (r8): no asm pins, no in-loop cvt. Weights come from the PACKED
// buffer as plain dwordx4 loads -- cheap whether the allocator keeps them
// resident or sinks them (L2-hit, off the serial chain). xg is staged
// through LDS in 4-step double-buffered chunks (HBM latency off-chain,
// amortized across 4 steps). hs accumulates in LDS, dumped after the loop
// (no global stores inside the loop for the barrier drain to wait on).
// ---------------------------------------------------------------------------
__global__
__attribute__((amdgpu_flat_work_group_size(256, 256), amdgpu_waves_per_eu(1, 1)))
void scan_kernel(
    const _Float16* __restrict__ Wp,
    const float* __restrict__ xgp,
    float* __restrict__ hs)
{
    const int tid  = threadIdx.x;
    const int lane = tid & 63;
    const int w    = tid >> 6;        // wave id 0..3
    const int col  = lane & 15;
    const int quad = lane >> 4;
    const int wbase = w * 32;
    const bool sel  = (lane >= 32);
    const int jsel  = wbase + (sel ? 16 : 0) + col; // hidden index this lane updates
    const int aoff  = quad * 8;

    __shared__ __align__(16) _Float16 h_lds[2][HH];          // 512 B
    __shared__ __align__(16) float xgc[2][4][HH][4];         // 16 KB
    __shared__ __align__(16) float hs_l[BB * HH];            // 128 KB

    // ---- B-fragments: plain contiguous 16-B loads from the packed buffer ----
#define BLOADP(nt, kt) \
    half8 B##nt##_##kt = *(const half8*)(Wp + (((w * 32 + (nt) * 4 + (kt)) * 64 + lane) * 8));
#define FOR_KT(X, nt) X(nt, 0) X(nt, 1) X(nt, 2) X(nt, 3)
#define FOR_NT(X) FOR_KT(X, 0) FOR_KT(X, 1) FOR_KT(X, 2) FOR_KT(X, 3) \
                  FOR_KT(X, 4) FOR_KT(X, 5) FOR_KT(X, 6) FOR_KT(X, 7)
    FOR_NT(BLOADP)

    if (tid < HH) h_lds[0][tid] = (_Float16)0.f;

    // preload xg chunk 0 into xgc[0] (8 KB = 512 float4; 2 per thread)
    {
        const f32x4* src = (const f32x4*)xgp;
        f32x4 a = src[2 * tid], b = src[2 * tid + 1];
        f32x4* dst = (f32x4*)&xgc[0][0][0][0];
        dst[2 * tid] = a; dst[2 * tid + 1] = b;
    }
    float c = 0.f;
    int p = 0;
    __syncthreads();

    f32x4 pf0, pf1;   // next-chunk prefetch registers

    for (int ch = 0; ch < NCH; ch++) {
        const int buf = ch & 1;
        // issue next chunk's global loads immediately after the barrier:
        // consumed (ds_write) at k==3, ~3.5 steps of slack over HBM latency.
        if (ch + 1 < NCH) {
            const f32x4* src = (const f32x4*)(xgp + (ch + 1) * 4 * GG);
            pf0 = src[2 * tid];
            pf1 = src[2 * tid + 1];
        }
#pragma unroll
        for (int k = 0; k < 4; k++) {
            const int t = ch * 4 + k;

            // A-fragments: h replicated over all 16 rows
            const _Float16* hl = h_lds[p];
            half8 A0 = *(const half8*)(hl + 0 * 32 + aoff);
            half8 A1 = *(const half8*)(hl + 1 * 32 + aoff);
            half8 A2 = *(const half8*)(hl + 2 * 32 + aoff);
            half8 A3 = *(const half8*)(hl + 3 * 32 + aoff);

            // this step's packed gate biases (one ds_read_b128)
            f32x4 xgv = *(const f32x4*)&xgc[buf][k][jsel][0];

            f32x4 C0 = {0.f,0.f,0.f,0.f}, C1 = {0.f,0.f,0.f,0.f};
            f32x4 C2 = {0.f,0.f,0.f,0.f}, C3 = {0.f,0.f,0.f,0.f};
            f32x4 C4 = {0.f,0.f,0.f,0.f}, C5 = {0.f,0.f,0.f,0.f};
            f32x4 C6 = {0.f,0.f,0.f,0.f}, C7 = {0.f,0.f,0.f,0.f};
#define MF(nt, kt) \
            C##nt = __builtin_amdgcn_mfma_f32_16x16x32_f16(A##kt, B##nt##_##kt, C##nt, 0, 0, 0);
#define MF_ALLNT(kt) MF(0, kt) MF(1, kt) MF(2, kt) MF(3, kt) \
                     MF(4, kt) MF(5, kt) MF(6, kt) MF(7, kt)
            MF_ALLNT(0) MF_ALLNT(1) MF_ALLNT(2) MF_ALLNT(3)

            float pi = (sel ? C1[0] : C0[0]) + xgv.x;
            float pf = (sel ? C3[0] : C2[0]) + xgv.y;
            float pg = (sel ? C5[0] : C4[0]) + xgv.z;
            float po = (sel ? C7[0] : C6[0]) + xgv.w;

            float iv = sigmoid_fast(pi);
            float fv = sigmoid_fast(pf);
            float gv = tanh_fast(pg);
            float ov = sigmoid_fast(po);

            c = fv * c + iv * gv;
            float hval = ov * tanh_fast(c);

            // one writer pair per hidden index (quads 0 and 3)
            if (quad == 0 || quad == 3) {
                h_lds[1 - p][jsel] = (_Float16)hval;
                if (t >= TT - BB) hs_l[(t - (TT - BB)) * HH + jsel] = hval;
            }

            // stage the prefetched chunk into the other LDS buffer
            if (k == 3 && ch + 1 < NCH) {
                f32x4* dst = (f32x4*)&xgc[1 - buf][0][0][0];
                dst[2 * tid] = pf0;
                dst[2 * tid + 1] = pf1;
            }

            p ^= 1;
            __syncthreads();
        }
    }

    // dump hs (128 KB LDS -> global, coalesced)
    const f32x4* s = (const f32x4*)hs_l;
    f32x4* d = (f32x4*)hs;
#pragma unroll 4
    for (int i = tid; i < BB * HH / 4; i += 256) d[i] = s[i];
}

// ---------------------------------------------------------------------------
// Kernel 3: out[r,:] = W2 @ (W1 @ hs[r] + b1) + b2  (no activation in ref)
// ---------------------------------------------------------------------------
__global__ __launch_bounds__(128) void mlp_kernel(
    const float* __restrict__ hs,
    const float* __restrict__ W1,
    const float* __restrict__ b1,
    const float* __restrict__ W2,
    const float* __restrict__ b2,
    float* __restrict__ out)
{
    const int r = blockIdx.x;
    const int j = threadIdx.x;

    __shared__ __align__(16) float hsh[HH];
    __shared__ __align__(16) float z[HH];

    hsh[j] = hs[r * HH + j];
    __syncthreads();

    {
        const float4* __restrict__ wrow = (const float4*)(W1 + j * HH);
        const float4* __restrict__ hv   = (const float4*)hsh;
        float acc = b1[j];
#pragma unroll
        for (int i = 0; i < 32; i++) {
            float4 ww = wrow[i], h = hv[i];
            acc += ww.x * h.x + ww.y * h.y + ww.z * h.z + ww.w * h.w;
        }
        z[j] = acc;
    }
    __syncthreads();

    if (j < OO) {
        const float4* __restrict__ wrow = (const float4*)(W2 + j * HH);
        const float4* __restrict__ zv   = (const float4*)z;
        float acc = b2[j];
#pragma unroll
        for (int i = 0; i < 32; i++) {
            float4 ww = wrow[i], zz = zv[i];
            acc += ww.x * zz.x + ww.y * zz.y + ww.z * zz.z + ww.w * zz.w;
        }
        out[r * OO + j] = acc;
    }
}

// ---------------------------------------------------------------------------
// Launch. Inputs: 0:x 1:W_ih 2:W_hh 3:b_ih 4:b_hh 5:W1 6:b1 7:W2 8:b2
// ws: xg packed (1 MB) | hs (128 KB) | Wp packed f16 frags (128 KB)
// ---------------------------------------------------------------------------
extern "C" void kernel_launch(void* const* d_in, const int* in_sizes, int n_in,
                              void* d_out, int out_size, void* d_ws, size_t ws_size,
                              hipStream_t stream) {
    const float* x    = (const float*)d_in[0];
    const float* W_ih = (const float*)d_in[1];
    const float* W_hh = (const float*)d_in[2];
    const float* b_ih = (const float*)d_in[3];
    const float* b_hh = (const float*)d_in[4];
    const float* W1   = (const float*)d_in[5];
    const float* b1   = (const float*)d_in[6];
    const float* W2   = (const float*)d_in[7];
    const float* b2   = (const float*)d_in[8];
    float* out = (float*)d_out;

    float*    xg = (float*)d_ws;                 // T*4H   = 262144 f32 (packed)
    float*    hs = xg + TT * GG;                 // 256*H  =  32768 f32
    _Float16* Wp = (_Float16*)(hs + BB * HH);    // 4H*H   =  65536 f16 (packed frags)

    wpack_kernel<<<32, 256, 0, stream>>>(W_hh, Wp);
    xg_kernel<<<TT, 512, 0, stream>>>(x, W_ih, b_ih, b_hh, xg);
    scan_kernel<<<1, 256, 0, stream>>>(Wp, xg, hs);
    mlp_kernel<<<BB, 128, 0, stream>>>(hs, W1, b1, W2, b2, out);
}